// Round 1
// baseline (263.685 us; speedup 1.0000x reference)
//
#include <hip/hip_runtime.h>
#include <stdint.h>

#define EPS_F 1e-3f

// Sizes
#define NB 8192   // batch rows
#define NP 4096   // prototypes
#define ND 512    // feature dim
#define NC 1000   // classes
#define NCP 1024  // padded classes

typedef __attribute__((ext_vector_type(8))) short short8;
typedef __attribute__((ext_vector_type(4))) float floatx4;

static __device__ __forceinline__ unsigned short f2bf(float f) {
  union { float f; unsigned u; } v; v.f = f;
  unsigned u = v.u;
  u += 0x7fffu + ((u >> 16) & 1u);   // round-to-nearest-even
  return (unsigned short)(u >> 16);
}

static __device__ __forceinline__ void gl_lds16(const void* g, void* l) {
  __builtin_amdgcn_global_load_lds(
      (const __attribute__((address_space(1))) void*)g,
      (__attribute__((address_space(3))) void*)l,
      16, 0, 0);
}

// ---------------------------------------------------------------------------
// prep: convert X,K to bf16 + fp32 row norms; transpose V -> Vt bf16 [NCP][NP]
// (zero-padded rows for c>=1000); zero rowsum.
// grid: 2048 (X) + 1024 (K) + 4096 (V transpose) = 7168 blocks x 256
// ---------------------------------------------------------------------------
__global__ __launch_bounds__(256) void prep_kernel(
    const float* __restrict__ X, const float* __restrict__ Kk,
    const float* __restrict__ V,
    unsigned short* __restrict__ Xb, unsigned short* __restrict__ Kb,
    unsigned short* __restrict__ Vt,
    float* __restrict__ xnorm, float* __restrict__ knorm,
    float* __restrict__ rowsum) {
  const int b = blockIdx.x;
  const int tid = threadIdx.x;
  __shared__ float tile[32][33];

  if (b < 3072) {
    const float* src;
    unsigned short* dst;
    float* nrm;
    int rbase;
    if (b < 2048) {
      src = X; dst = Xb; nrm = xnorm; rbase = b * 4;
      if (tid < 4) rowsum[b * 4 + tid] = 0.0f;
    } else {
      src = Kk; dst = Kb; nrm = knorm; rbase = (b - 2048) * 4;
    }
    const int w = tid >> 6, l = tid & 63;
    const int r = rbase + w;
    const float* p = src + (size_t)r * ND + l * 8;
    float4 v0 = *(const float4*)p;
    float4 v1 = *(const float4*)(p + 4);
    float s = v0.x * v0.x + v0.y * v0.y + v0.z * v0.z + v0.w * v0.w +
              v1.x * v1.x + v1.y * v1.y + v1.z * v1.z + v1.w * v1.w;
    short8 pk;
    pk[0] = (short)f2bf(v0.x); pk[1] = (short)f2bf(v0.y);
    pk[2] = (short)f2bf(v0.z); pk[3] = (short)f2bf(v0.w);
    pk[4] = (short)f2bf(v1.x); pk[5] = (short)f2bf(v1.y);
    pk[6] = (short)f2bf(v1.z); pk[7] = (short)f2bf(v1.w);
    *(short8*)(dst + (size_t)r * ND + l * 8) = pk;
    for (int off = 32; off > 0; off >>= 1) s += __shfl_xor(s, off, 64);
    if (l == 0) nrm[r] = s;
  } else {
    // values transpose: V [NP][NC] f32 -> Vt [NCP][NP] bf16
    const int t = b - 3072;
    const int pt = t & 127, ct = t >> 7;    // 128 p-tiles, 32 c-tiles
    const int p0 = pt * 32, c0 = ct * 32;
    const int i = tid >> 3, j4 = (tid & 7) * 4;
    const float* vp = V + (size_t)(p0 + i) * NC;
    for (int u = 0; u < 4; ++u) {
      int c = c0 + j4 + u;
      tile[i][j4 + u] = (c < NC) ? vp[c] : 0.0f;
    }
    __syncthreads();
    const int j = tid >> 3, i4 = (tid & 7) * 4;
    uint2 pk;
    pk.x = (unsigned)f2bf(tile[i4 + 0][j]) | ((unsigned)f2bf(tile[i4 + 1][j]) << 16);
    pk.y = (unsigned)f2bf(tile[i4 + 2][j]) | ((unsigned)f2bf(tile[i4 + 3][j]) << 16);
    *(uint2*)(Vt + (size_t)(c0 + j) * NP + p0 + i4) = pk;
  }
}

// ---------------------------------------------------------------------------
// Shared MFMA GEMM core: C[128x128] += A[128xKD] * B[128xKD]^T, bf16 inputs,
// both row-major with K contiguous. 256 threads = 4 waves in 2x2, each wave
// does a 64x64 subtile = 4x4 MFMA 16x16x32 accumulators.
// LDS tiles are [row][32] with a 16B-chunk XOR swizzle (chunk ^= (row>>1)&3)
// so ds_read_b128 fragment loads are bank-conflict free while the
// global_load_lds fill stays lane-contiguous.
// ---------------------------------------------------------------------------
template <int KD>
static __device__ __forceinline__ void gemm_core(
    const unsigned short* __restrict__ gA,  // + bm*KD applied by caller
    const unsigned short* __restrict__ gB,  // + bn*KD applied by caller
    unsigned short* lA, unsigned short* lB, floatx4 (&acc)[4][4]) {
  const int tid = threadIdx.x;
  const int w = tid >> 6, lane = tid & 63;
  const int wm = w >> 1, wn = w & 1;
  const int lm = lane & 15, q = lane >> 4;
  const int srow = lane >> 2;    // row within a 16-row staging group
  const int c_lds = lane & 3;    // 16B chunk within 64B row
  const int sw = (lm >> 1) & 3;  // read-side swizzle

  for (int k0 = 0; k0 < KD; k0 += 32) {
    for (int t = 0; t < 2; ++t) {
      const int row0 = w * 32 + t * 16;
      const int row = row0 + srow;
      const int cg = c_lds ^ ((row >> 1) & 3);
      gl_lds16(gA + (size_t)row * KD + k0 + cg * 8, &lA[row0 * 32]);
      gl_lds16(gB + (size_t)row * KD + k0 + cg * 8, &lB[row0 * 32]);
    }
    __syncthreads();
    short8 af[4], bf[4];
    for (int t = 0; t < 4; ++t) {
      const int ra = wm * 64 + t * 16 + lm;
      af[t] = *(const short8*)&lA[ra * 32 + (q ^ sw) * 8];
      const int rb = wn * 64 + t * 16 + lm;
      bf[t] = *(const short8*)&lB[rb * 32 + (q ^ sw) * 8];
    }
    for (int i = 0; i < 4; ++i)
      for (int j = 0; j < 4; ++j)
        acc[i][j] = __builtin_amdgcn_mfma_f32_16x16x32_bf16(af[i], bf[j],
                                                            acc[i][j], 0, 0, 0);
    __syncthreads();
  }
}

// GEMM1: S = Xb * Kb^T, fused epilogue -> attn_u bf16 + rowsum atomics
__global__ __launch_bounds__(256, 3) void gemm1_kernel(
    const unsigned short* __restrict__ A, const unsigned short* __restrict__ B,
    const float* __restrict__ xnorm, const float* __restrict__ knorm,
    unsigned short* __restrict__ attn, float* __restrict__ rowsum) {
  __shared__ __align__(16) unsigned short lA[128 * 32];
  __shared__ __align__(16) unsigned short lB[128 * 32];
  const int tid = threadIdx.x;
  const int w = tid >> 6, lane = tid & 63;
  const int wm = w >> 1, wn = w & 1;
  const int lm = lane & 15, q = lane >> 4;
  const int bm = blockIdx.y * 128, bn = blockIdx.x * 128;

  floatx4 acc[4][4];
  for (int i = 0; i < 4; ++i)
    for (int j = 0; j < 4; ++j) acc[i][j] = (floatx4)(0.0f);

  gemm_core<ND>(A + (size_t)bm * ND, B + (size_t)bn * ND, lA, lB, acc);

  for (int i = 0; i < 4; ++i) {
    for (int r = 0; r < 4; ++r) {
      const int grow = bm + wm * 64 + i * 16 + q * 4 + r;
      const float xn = xnorm[grow];
      float rs = 0.0f;
      for (int j = 0; j < 4; ++j) {
        const int gcol = bn + wn * 64 + j * 16 + lm;
        float sq = xn + knorm[gcol] - 2.0f * acc[i][j][r];
        sq = fmaxf(sq, 0.0f);
        float a = 1.0f / (EPS_F + sq);
        rs += a;
        attn[(size_t)grow * NP + gcol] = f2bf(a);
      }
      rs += __shfl_xor(rs, 1, 16);
      rs += __shfl_xor(rs, 2, 16);
      rs += __shfl_xor(rs, 4, 16);
      rs += __shfl_xor(rs, 8, 16);
      if (lm == 0) atomicAdd(&rowsum[grow], rs);
    }
  }
}

// GEMM2: logits = (attn_u * Vt^T) / rowsum
__global__ __launch_bounds__(256, 3) void gemm2_kernel(
    const unsigned short* __restrict__ A, const unsigned short* __restrict__ B,
    const float* __restrict__ rowsum, float* __restrict__ out) {
  __shared__ __align__(16) unsigned short lA[128 * 32];
  __shared__ __align__(16) unsigned short lB[128 * 32];
  const int tid = threadIdx.x;
  const int w = tid >> 6, lane = tid & 63;
  const int wm = w >> 1, wn = w & 1;
  const int lm = lane & 15, q = lane >> 4;
  const int bm = blockIdx.y * 128, bn = blockIdx.x * 128;

  floatx4 acc[4][4];
  for (int i = 0; i < 4; ++i)
    for (int j = 0; j < 4; ++j) acc[i][j] = (floatx4)(0.0f);

  gemm_core<NP>(A + (size_t)bm * NP, B + (size_t)bn * NP, lA, lB, acc);

  for (int i = 0; i < 4; ++i) {
    for (int r = 0; r < 4; ++r) {
      const int grow = bm + wm * 64 + i * 16 + q * 4 + r;
      const float inv = 1.0f / rowsum[grow];
      for (int j = 0; j < 4; ++j) {
        const int gcol = bn + wn * 64 + j * 16 + lm;
        if (gcol < NC) out[(size_t)grow * NC + gcol] = acc[i][j][r] * inv;
      }
    }
  }
}

// ---------------------------------------------------------------------------
extern "C" void kernel_launch(void* const* d_in, const int* in_sizes, int n_in,
                              void* d_out, int out_size, void* d_ws,
                              size_t ws_size, hipStream_t stream) {
  const float* X = (const float*)d_in[0];   // [8192][512]
  const float* Kk = (const float*)d_in[1];  // [4096][512]
  const float* V = (const float*)d_in[2];   // [4096][1000]
  float* out = (float*)d_out;               // [8192][1000]
  char* ws = (char*)d_ws;

  // workspace layout (bytes)
  unsigned short* Xb = (unsigned short*)(ws + 0);          //  8,388,608
  unsigned short* Kb = (unsigned short*)(ws + 8388608);    //  4,194,304
  unsigned short* Vt = (unsigned short*)(ws + 12582912);   //  8,388,608
  unsigned short* attn = (unsigned short*)(ws + 20971520); // 67,108,864
  float* xnorm = (float*)(ws + 88080384);                  //     32,768
  float* knorm = (float*)(ws + 88113152);                  //     16,384
  float* rowsum = (float*)(ws + 88129536);                 //     32,768

  prep_kernel<<<7168, 256, 0, stream>>>(X, Kk, V, Xb, Kb, Vt, xnorm, knorm,
                                        rowsum);
  gemm1_kernel<<<dim3(NP / 128, NB / 128), 256, 0, stream>>>(Xb, Kb, xnorm,
                                                             knorm, attn,
                                                             rowsum);
  gemm2_kernel<<<dim3(NCP / 128, NB / 128), 256, 0, stream>>>(attn, Vt, rowsum,
                                                              out);
}